// Round 1
// baseline (556.423 us; speedup 1.0000x reference)
//
#include <hip/hip_runtime.h>
#include <math.h>

// ---------------------------------------------------------------------------
// VQVAE forward, fp32 end-to-end.
// Outputs (concat float32): x_hat[32*3*128*128], idx[2048] (as float),
//                           vq_loss[1], z_e[32*64*8*8]
// Decoder trick: dconv1 on the x16-nearest-upsampled image has only 9
// distinct output vectors per 16x16 block -> 25 aggregated 128x128 matrices.
// ---------------------------------------------------------------------------

// ---------- transpose enc_w2 -> w2t[k=ci*9+tap][co] ----------
__global__ __launch_bounds__(256) void k_w2t(const float* __restrict__ w2,
                                             float* __restrict__ w2t) {
  int i = blockIdx.x * 256 + threadIdx.x;  // 1152*128 = 147456
  if (i >= 1152 * 128) return;
  int k = i >> 7, co = i & 127;
  w2t[i] = w2[co * 1152 + k];
}

// ---------- conv1: (32,3,128,128) -> (32,128,64,64), 3x3 s2 p1, relu ----------
// grid (8, 64, 32) = (co_chunk, oh, b), block 256
__global__ __launch_bounds__(256) void k_conv1(const float* __restrict__ x,
                                               const float* __restrict__ w1,
                                               const float* __restrict__ b1,
                                               float* __restrict__ h1) {
  __shared__ float xs[3][3][130];
  __shared__ float wl[16][28];
  int co16 = blockIdx.x * 16, oh = blockIdx.y, b = blockIdx.z;
  int tid = threadIdx.x;
  for (int i = tid; i < 3 * 3 * 130; i += 256) {
    int ci = i / 390, rem = i - ci * 390;
    int r = rem / 130, iwp = rem - r * 130;
    int ih = 2 * oh - 1 + r, iw = iwp - 1;
    float v = 0.f;
    if (ih >= 0 && ih < 128 && iw >= 0 && iw < 128)
      v = x[((b * 3 + ci) * 128 + ih) * 128 + iw];
    xs[ci][r][iwp] = v;
  }
  for (int i = tid; i < 16 * 27; i += 256) {
    int c = i / 27, t = i - c * 27;
    wl[c][t] = w1[(co16 + c) * 27 + t];
  }
  __syncthreads();
  int lane = tid & 63, wv = tid >> 6;
  float acc[4];
#pragma unroll
  for (int q = 0; q < 4; q++) acc[q] = b1[co16 + wv * 4 + q];
#pragma unroll
  for (int ci = 0; ci < 3; ci++)
#pragma unroll
    for (int ky = 0; ky < 3; ky++)
#pragma unroll
      for (int kx = 0; kx < 3; kx++) {
        float xv = xs[ci][ky][2 * lane + kx];
        int t = ci * 9 + ky * 3 + kx;
#pragma unroll
        for (int q = 0; q < 4; q++) acc[q] += wl[wv * 4 + q][t] * xv;
      }
#pragma unroll
  for (int q = 0; q < 4; q++) {
    int co = co16 + wv * 4 + q;
    h1[((b * 128 + co) * 64 + oh) * 64 + lane] = fmaxf(acc[q], 0.f);
  }
}

// ---------- conv2: (32,128,64,64) -> (32,128,32,32), 3x3 s2 p1, relu ----------
// grid (2, 16, 32) = (co_tile, oh_pair, b), block 256, 64co x 64px tile, 4x4/thread
__global__ __launch_bounds__(256) void k_conv2(const float* __restrict__ h1,
                                               const float* __restrict__ w2t,
                                               const float* __restrict__ b2,
                                               float* __restrict__ h2) {
  __shared__ float raw[8][5][68];   // [ci][ih_local][iw+1]
  __shared__ float wt[72][64];      // [k=ci*9+tap][co_local]
  int co_t = blockIdx.x, oh0 = blockIdx.y * 2, b = blockIdx.z;
  int tid = threadIdx.x;
  int tx = tid & 15, ty = tid >> 4;
  int r0 = tx >> 3, ow0 = (tx & 7) * 4;  // px frag: oh = oh0+r0, ow = ow0..+3
  float acc[4][4];
#pragma unroll
  for (int i = 0; i < 4; i++)
#pragma unroll
    for (int j = 0; j < 4; j++) acc[i][j] = 0.f;

  for (int ci0 = 0; ci0 < 128; ci0 += 8) {
    __syncthreads();
    for (int i = tid; i < 8 * 5 * 68; i += 256) {
      int ci = i / 340, rem = i - ci * 340;
      int rr = rem / 68, iwp = rem - rr * 68;
      int ih = 2 * oh0 - 1 + rr, iw = iwp - 1;
      float v = 0.f;
      if (ih >= 0 && ih < 64 && iw >= 0 && iw < 64)
        v = h1[((b * 128 + ci0 + ci) * 64 + ih) * 64 + iw];
      raw[ci][rr][iwp] = v;
    }
    for (int i = tid; i < 72 * 64; i += 256) {
      int k = i >> 6, c = i & 63;
      wt[k][c] = w2t[(ci0 * 9 + k) * 128 + co_t * 64 + c];
    }
    __syncthreads();
    for (int ci = 0; ci < 8; ci++) {
#pragma unroll
      for (int ky = 0; ky < 3; ky++)
#pragma unroll
        for (int kx = 0; kx < 3; kx++) {
          int k = ci * 9 + ky * 3 + kx;
          float a[4], bb[4];
#pragma unroll
          for (int i = 0; i < 4; i++) a[i] = wt[k][ty * 4 + i];
#pragma unroll
          for (int j = 0; j < 4; j++)
            bb[j] = raw[ci][2 * r0 + ky][2 * (ow0 + j) + kx];
#pragma unroll
          for (int i = 0; i < 4; i++)
#pragma unroll
            for (int j = 0; j < 4; j++) acc[i][j] += a[i] * bb[j];
        }
    }
  }
  int oh = oh0 + r0;
#pragma unroll
  for (int i = 0; i < 4; i++) {
    int co = co_t * 64 + ty * 4 + i;
    float bias = b2[co];
#pragma unroll
    for (int j = 0; j < 4; j++) {
      h2[((b * 128 + co) * 32 + oh) * 32 + ow0 + j] = fmaxf(acc[i][j] + bias, 0.f);
    }
  }
}

// ---------- pool(4x4 mean) + proj(1x1, 128->64) -> z_e ----------
// grid 32 (b), block 256
__global__ __launch_bounds__(256) void k_poolproj(const float* __restrict__ h2,
                                                  const float* __restrict__ wp,
                                                  const float* __restrict__ pb,
                                                  float* __restrict__ z_e_out) {
  __shared__ float hp[128][64];
  __shared__ float wps[64][128];
  int b = blockIdx.x, tid = threadIdx.x;
  for (int i = tid; i < 8192; i += 256) wps[i >> 7][i & 127] = wp[i];
  for (int i = tid; i < 8192; i += 256) {
    int ci = i >> 6, pi = i & 63;
    int bi = pi >> 3, bj = pi & 7;
    const float* src = &h2[((b * 128 + ci) * 32 + bi * 4) * 32 + bj * 4];
    float s = 0.f;
#pragma unroll
    for (int u = 0; u < 4; u++)
#pragma unroll
      for (int v = 0; v < 4; v++) s += src[u * 32 + v];
    hp[ci][pi] = s * 0.0625f;
  }
  __syncthreads();
  int pi = tid & 63, dg = tid >> 6;
  for (int j = 0; j < 16; j++) {
    int d = dg * 16 + j;
    float acc = pb[d];
#pragma unroll 4
    for (int ci = 0; ci < 128; ci++) acc += wps[d][ci] * hp[ci][pi];
    z_e_out[(b * 64 + d) * 64 + pi] = acc;
  }
}

// ---------- VQ: argmin over 512 codes, loss accum ----------
// grid 2048 (n), block 64 (one wave)
__global__ __launch_bounds__(64) void k_vq(const float* __restrict__ z_e,
                                           const float* __restrict__ cb,
                                           float* __restrict__ idx_f,
                                           int* __restrict__ idx_i,
                                           float* __restrict__ loss_acc) {
  __shared__ float zs[64];
  int n = blockIdx.x, lane = threadIdx.x;
  int b = n >> 6, pi = n & 63;
  zs[lane] = z_e[(b * 64 + lane) * 64 + pi];
  __syncthreads();
  double best = 1e300;
  int bi = 0;
  for (int j = 0; j < 8; j++) {
    int k = j * 64 + lane;
    const float* c = &cb[k * 64];
    double acc = 0.0;
#pragma unroll 8
    for (int d = 0; d < 64; d++) {
      double diff = (double)zs[d] - (double)c[d];
      acc += diff * diff;
    }
    if (acc < best) { best = acc; bi = k; }  // ascending k: first-min kept
  }
  for (int m = 1; m < 64; m <<= 1) {
    double ob = __shfl_xor(best, m, 64);
    int oi = __shfl_xor(bi, m, 64);
    if (ob < best || (ob == best && oi < bi)) { best = ob; bi = oi; }
  }
  float e = cb[bi * 64 + lane] - zs[lane];
  float sq = e * e;
  for (int m = 1; m < 64; m <<= 1) sq += __shfl_xor(sq, m, 64);
  if (lane == 0) {
    idx_f[n] = (float)bi;
    idx_i[n] = bi;
    atomicAdd(loss_acc, sq);
  }
}

__global__ void k_loss(const float* __restrict__ loss_acc, float* __restrict__ out_loss) {
  out_loss[0] = loss_acc[0] * 1.25f / 131072.0f;
}

// ---------- aggregate dconv1 weights (25 matrices) + transpose dproj_w ----------
__global__ __launch_bounds__(256) void k_amat(const float* __restrict__ wd1,
                                              float* __restrict__ A,
                                              const float* __restrict__ wdp,
                                              float* __restrict__ wdT) {
  int i = blockIdx.x * 256 + threadIdx.x;
  const int ymask[5] = {1, 6, 7, 3, 4};  // {ky0},{ky1,2},{all},{ky0,1},{ky2}
  if (i < 25 * 128 * 128) {
    int pq = i >> 14, rem = i & 16383;
    int ci = rem >> 7, co = rem & 127;
    int py = pq / 5, px = pq - py * 5;
    int my = ymask[py], mx = ymask[px];
    float s = 0.f;
    for (int ky = 0; ky < 3; ky++)
      if (my & (1 << ky))
        for (int kx = 0; kx < 3; kx++)
          if (mx & (1 << kx)) s += wd1[((co * 128 + ci) * 3 + ky) * 3 + kx];
    A[i] = s;
  }
  int j = i - 25 * 128 * 128;
  if (j >= 0 && j < 64 * 128) {
    int d = j >> 7, co = j & 127;
    wdT[j] = wdp[co * 64 + d];
  }
}

// ---------- dproj(1x1, 64->128) + relu -> Yr (32,128,8,8) ----------
// grid 2048 (n), block 128
__global__ __launch_bounds__(128) void k_dproj(const int* __restrict__ idx_i,
                                               const float* __restrict__ cb,
                                               const float* __restrict__ wdT,
                                               const float* __restrict__ db,
                                               float* __restrict__ Yr) {
  __shared__ float zq[64];
  int n = blockIdx.x, tid = threadIdx.x;
  int b = n >> 6, pi = n & 63;
  int id = idx_i[n];
  if (tid < 64) zq[tid] = cb[id * 64 + tid];
  __syncthreads();
  float acc = db[tid];
#pragma unroll 4
  for (int d = 0; d < 64; d++) acc += wdT[d * 128 + tid] * zq[d];
  Yr[(b * 128 + tid) * 64 + pi] = fmaxf(acc, 0.f);
}

// ---------- decoder block-conv: 9 classes, GEMM vs aggregated matrices ----------
// grid (2, 32, 9) = (co_tile, b, cls), block 256, 64co x 64n tile, 4x4/thread
__global__ __launch_bounds__(256) void k_dec(const float* __restrict__ Yr,
                                             const float* __restrict__ A,
                                             const float* __restrict__ bc1,
                                             float* __restrict__ T) {
  __shared__ float As[16][64];
  __shared__ float Bs[16][64];
  int co_t = blockIdx.x, b = blockIdx.y, cls = blockIdx.z;
  int r = cls / 3, c = cls - r * 3;
  const int pTab[3][2] = {{0, 1}, {2, 2}, {3, 4}};
  const int dTab[3][2] = {{-1, 0}, {0, 0}, {0, 1}};
  const int nTab[3] = {2, 1, 2};
  int tid = threadIdx.x;
  int tx = tid & 15, ty = tid >> 4;
  int n0 = tx * 4, co0 = ty * 4;
  float acc[4][4];
#pragma unroll
  for (int i = 0; i < 4; i++)
#pragma unroll
    for (int j = 0; j < 4; j++) acc[i][j] = 0.f;

  for (int iy = 0; iy < nTab[r]; iy++) {
    int py = pTab[r][iy], dy = dTab[r][iy];
    for (int ix = 0; ix < nTab[c]; ix++) {
      int px = pTab[c][ix], dx = dTab[c][ix];
      const float* Apq = &A[(py * 5 + px) * 16384];
      for (int ci0 = 0; ci0 < 128; ci0 += 16) {
        __syncthreads();
        for (int i = tid; i < 1024; i += 256) {
          int kk = i >> 6, cc = i & 63;
          As[kk][cc] = Apq[(ci0 + kk) * 128 + co_t * 64 + cc];
        }
        for (int i = tid; i < 1024; i += 256) {
          int kk = i >> 6, nn = i & 63;
          int bi = nn >> 3, bj = nn & 7;
          int sy = bi + dy, sx = bj + dx;
          float v = 0.f;
          if (sy >= 0 && sy < 8 && sx >= 0 && sx < 8)
            v = Yr[(b * 128 + ci0 + kk) * 64 + sy * 8 + sx];
          Bs[kk][nn] = v;
        }
        __syncthreads();
#pragma unroll
        for (int kk = 0; kk < 16; kk++) {
          float a[4], bb[4];
#pragma unroll
          for (int i = 0; i < 4; i++) a[i] = As[kk][co0 + i];
#pragma unroll
          for (int j = 0; j < 4; j++) bb[j] = Bs[kk][n0 + j];
#pragma unroll
          for (int i = 0; i < 4; i++)
#pragma unroll
            for (int j = 0; j < 4; j++) acc[i][j] += a[i] * bb[j];
        }
      }
    }
  }
#pragma unroll
  for (int i = 0; i < 4; i++) {
    int co = co_t * 64 + co0 + i;
    float bias = bc1[co];
#pragma unroll
    for (int j = 0; j < 4; j++)
      T[((cls * 32 + b) * 128 + co) * 64 + n0 + j] = fmaxf(acc[i][j] + bias, 0.f);
  }
}

// ---------- dconv2 (1x1, 128->3) + splat to x_hat ----------
// grid (8,8,32) = (bj, bi, b), block 256
__global__ __launch_bounds__(256) void k_out(const float* __restrict__ T,
                                             const float* __restrict__ w3,
                                             const float* __restrict__ b3,
                                             float* __restrict__ xhat) {
  __shared__ float Tb[9][128];
  __shared__ float part[9][3][8];
  __shared__ float vals[9][3];
  int bj = blockIdx.x, bi = blockIdx.y, b = blockIdx.z;
  int nn = bi * 8 + bj;
  int tid = threadIdx.x;
  for (int i = tid; i < 1152; i += 256) {
    int cls = i >> 7, co = i & 127;
    Tb[cls][co] = T[((cls * 32 + b) * 128 + co) * 64 + nn];
  }
  __syncthreads();
  if (tid < 216) {
    int cls = tid / 24, rem = tid - cls * 24;
    int cc = rem >> 3, seg = rem & 7;
    float s = 0.f;
#pragma unroll
    for (int d = 0; d < 16; d++) s += w3[cc * 128 + seg * 16 + d] * Tb[cls][seg * 16 + d];
    part[cls][cc][seg] = s;
  }
  __syncthreads();
  if (tid < 27) {
    int cls = tid / 3, cc = tid - cls * 3;
    float s = b3[cc];
#pragma unroll
    for (int seg = 0; seg < 8; seg++) s += part[cls][cc][seg];
    vals[cls][cc] = s;
  }
  __syncthreads();
  for (int i = tid; i < 768; i += 256) {
    int cc = i >> 8, p = i & 255;
    int ry = p >> 4, rx = p & 15;
    int rcls = (ry == 0) ? 0 : ((ry == 15) ? 2 : 1);
    int ccls = (rx == 0) ? 0 : ((rx == 15) ? 2 : 1);
    xhat[((b * 3 + cc) * 128 + bi * 16 + ry) * 128 + bj * 16 + rx] =
        vals[rcls * 3 + ccls][cc];
  }
}

extern "C" void kernel_launch(void* const* d_in, const int* in_sizes, int n_in,
                              void* d_out, int out_size, void* d_ws, size_t ws_size,
                              hipStream_t stream) {
  const float* x   = (const float*)d_in[0];
  const float* w1  = (const float*)d_in[1];
  const float* b1  = (const float*)d_in[2];
  const float* w2  = (const float*)d_in[3];
  const float* b2  = (const float*)d_in[4];
  const float* wp  = (const float*)d_in[5];
  const float* pb  = (const float*)d_in[6];
  const float* cb  = (const float*)d_in[7];
  const float* wd  = (const float*)d_in[8];
  const float* db  = (const float*)d_in[9];
  const float* wc1 = (const float*)d_in[10];
  const float* bc1 = (const float*)d_in[11];
  const float* wc2 = (const float*)d_in[12];
  const float* bc2 = (const float*)d_in[13];
  float* out = (float*)d_out;
  float* ws  = (float*)d_ws;

  // workspace layout (floats). h1 region is reused by A/wdT/Yr/T after conv2.
  float* h1      = ws;                   // 16777216
  float* h2      = ws + 16777216;        // 4194304
  float* w2t     = ws + 20971520;        // 147456
  int*   idxi    = (int*)(ws + 21118976);// 2048
  float* lossacc = ws + 21121024;        // 1
  float* A       = ws;                   // 409600   (after k_conv2 done)
  float* wdT     = ws + 409600;          // 8192
  float* Yr      = ws + 417792;          // 262144
  float* T       = ws + 679936;          // 2359296

  float* o_xhat = out;
  float* o_idx  = out + 1572864;
  float* o_loss = out + 1574912;
  float* o_ze   = out + 1574913;

  hipMemsetAsync(lossacc, 0, sizeof(float), stream);
  k_w2t<<<dim3(576), 256, 0, stream>>>(w2, w2t);
  k_conv1<<<dim3(8, 64, 32), 256, 0, stream>>>(x, w1, b1, h1);
  k_conv2<<<dim3(2, 16, 32), 256, 0, stream>>>(h1, w2t, b2, h2);
  k_poolproj<<<dim3(32), 256, 0, stream>>>(h2, wp, pb, o_ze);
  k_amat<<<dim3(1632), 256, 0, stream>>>(wc1, A, wd, wdT);
  k_vq<<<dim3(2048), 64, 0, stream>>>(o_ze, cb, o_idx, idxi, lossacc);
  k_loss<<<dim3(1), 1, 0, stream>>>(lossacc, o_loss);
  k_dproj<<<dim3(2048), 128, 0, stream>>>(idxi, cb, wdT, db, Yr);
  k_dec<<<dim3(2, 32, 9), 256, 0, stream>>>(Yr, A, bc1, T);
  k_out<<<dim3(8, 8, 32), 256, 0, stream>>>(T, wc2, bc2, o_xhat);
}

// Round 2
// 501.902 us; speedup vs baseline: 1.1086x; 1.1086x over previous
//
#include <hip/hip_runtime.h>
#include <math.h>

// ---------------------------------------------------------------------------
// VQVAE forward, fp32 end-to-end. v2: wave-uniform weights via s_load
// (scalar pipe), phase-split LDS for stride-2 convs, decoder as 25 uniform
// batched GEMMs G[pq] = A_pq * shift(Y), combined per-class in k_out.
// ---------------------------------------------------------------------------

// ---------- prep: transposes (w2t, w1t, wpT, wdT) ----------
__global__ __launch_bounds__(256) void k_prep(const float* __restrict__ w2,
                                              const float* __restrict__ w1,
                                              const float* __restrict__ wp,
                                              const float* __restrict__ wd,
                                              float* __restrict__ w2t,
                                              float* __restrict__ w1t,
                                              float* __restrict__ wpT,
                                              float* __restrict__ wdT) {
  int i = blockIdx.x * 256 + threadIdx.x;
  if (i < 147456) {  // w2t[k][co] = w2[co][k], k<1152
    int k = i >> 7, co = i & 127;
    w2t[i] = w2[co * 1152 + k];
  }
  int j = i - 147456;
  if (j >= 0 && j < 3456) {  // w1t[t][co] = w1[co][t], t<27
    int t = j >> 7, co = j & 127;
    w1t[j] = w1[co * 27 + t];
  }
  int j2 = i - 150912;
  if (j2 >= 0 && j2 < 8192) {  // wpT[k][d] = wp[d][k]
    int k = j2 >> 6, d = j2 & 63;
    wpT[j2] = wp[d * 128 + k];
  }
  int j3 = i - 159104;
  if (j3 >= 0 && j3 < 8192) {  // wdT[d][co] = wd[co][d]
    int d = j3 >> 7, co = j3 & 127;
    wdT[j3] = wd[co * 64 + d];
  }
}

// ---------- prep2: aggregate dconv1 weights into 25 matrices A[pq][ci][co] ----
__global__ __launch_bounds__(256) void k_prep2(const float* __restrict__ wd1,
                                               float* __restrict__ A) {
  int i = blockIdx.x * 256 + threadIdx.x;  // 25*128*128 = 409600
  if (i >= 409600) return;
  const int ymask[5] = {1, 6, 7, 3, 4};  // {ky0},{ky1,2},{all},{ky0,1},{ky2}
  int pq = i >> 14, rem = i & 16383;
  int ci = rem >> 7, co = rem & 127;
  int py = pq / 5, px = pq - py * 5;
  int my = ymask[py], mx = ymask[px];
  float s = 0.f;
  for (int ky = 0; ky < 3; ky++)
    if (my & (1 << ky))
      for (int kx = 0; kx < 3; kx++)
        if (mx & (1 << kx)) s += wd1[((co * 128 + ci) * 3 + ky) * 3 + kx];
  A[i] = s;
}

// ---------- conv1: (32,3,128,128) -> (32,128,64,64), 3x3 s2 p1, relu ----------
// grid (4 co_t, 16 oh_t, 32 b), block 256. Wave owns 8 co; lane = 4 ow x 1 oh.
__global__ __launch_bounds__(256) void k_conv1(const float* __restrict__ x,
                                               const float* __restrict__ w1t,
                                               const float* __restrict__ b1,
                                               float* __restrict__ h1) {
  __shared__ float E[3][9][68];  // even cols: E[ci][lr][w] = x[ih][2w]
  __shared__ float O[3][9][68];  // odd cols:  O[ci][lr][u] = x[ih][2u-1]
  int co_t = blockIdx.x, oh_t = blockIdx.y, b = blockIdx.z;
  int oh0 = oh_t * 4;
  int tid = threadIdx.x;
  int wv = __builtin_amdgcn_readfirstlane(tid >> 6);
  int l = tid & 63;
  int coB = co_t * 32 + wv * 8;

  for (int idx = tid; idx < 1728; idx += 256) {  // 3ci*9lr*64p
    int p = idx & 63, r = idx >> 6;              // r<27
    int ci = r / 9, lr = r - ci * 9;
    int ih = 2 * oh0 - 1 + lr;
    float2 v = make_float2(0.f, 0.f);
    if ((unsigned)ih < 128u)
      v = *(const float2*)&x[((b * 3 + ci) * 128 + ih) * 128 + 2 * p];
    E[ci][lr][p] = v.x;
    O[ci][lr][p + 1] = v.y;
  }
  if (tid < 27) {
    int ci = tid / 9, lr = tid - ci * 9;
    O[ci][lr][0] = 0.f;  // iw = -1 pad
  }
  __syncthreads();

  int ohl = l >> 4, ow0 = (l & 15) * 4;
  int oh = oh0 + ohl;
  float4 acc[8];
#pragma unroll
  for (int q = 0; q < 8; q++) {
    float bv = b1[coB + q];
    acc[q] = make_float4(bv, bv, bv, bv);
  }
#pragma unroll
  for (int ci = 0; ci < 3; ci++) {
#pragma unroll
    for (int ky = 0; ky < 3; ky++) {
      int lr = 2 * ohl + ky;
      float4 ev = *(float4*)&E[ci][lr][ow0];
      float4 od = *(float4*)&O[ci][lr][ow0];
      float o4 = O[ci][lr][ow0 + 4];
      const float* wr = w1t + (ci * 9 + ky * 3) * 128 + coB;
#pragma unroll
      for (int q = 0; q < 8; q++) {
        float wa = wr[q], wb = wr[128 + q], wc = wr[256 + q];
        acc[q].x += wa * od.x + wb * ev.x + wc * od.y;
        acc[q].y += wa * od.y + wb * ev.y + wc * od.z;
        acc[q].z += wa * od.z + wb * ev.z + wc * od.w;
        acc[q].w += wa * od.w + wb * ev.w + wc * o4;
      }
    }
  }
#pragma unroll
  for (int q = 0; q < 8; q++) {
    float4 r4;
    r4.x = fmaxf(acc[q].x, 0.f);
    r4.y = fmaxf(acc[q].y, 0.f);
    r4.z = fmaxf(acc[q].z, 0.f);
    r4.w = fmaxf(acc[q].w, 0.f);
    *(float4*)&h1[((b * 128 + coB + q) * 64 + oh) * 64 + ow0] = r4;
  }
}

// ---------- conv2: (32,128,64,64) -> (32,128,32,32), 3x3 s2 p1, relu ----------
// grid (4 co_t, 4 px_t, 32 b), block 256. Wave owns 8 co; lane = 4 ow x (l>>3) oh.
__global__ __launch_bounds__(256) void k_conv2(const float* __restrict__ h1,
                                               const float* __restrict__ w2t,
                                               const float* __restrict__ b2,
                                               float* __restrict__ h2) {
  __shared__ float E[8][17][36];
  __shared__ float O[8][17][36];
  int co_t = blockIdx.x, px_t = blockIdx.y, b = blockIdx.z;
  int oh0 = px_t * 8;
  int tid = threadIdx.x;
  int wv = __builtin_amdgcn_readfirstlane(tid >> 6);
  int l = tid & 63;
  int coB = co_t * 32 + wv * 8;
  int ohl = l >> 3, ow0 = (l & 7) * 4;
  int oh = oh0 + ohl;

  float4 acc[8];
#pragma unroll
  for (int q = 0; q < 8; q++) {
    float bv = b2[coB + q];
    acc[q] = make_float4(bv, bv, bv, bv);
  }

  for (int ci0 = 0; ci0 < 128; ci0 += 8) {
    __syncthreads();
    for (int idx = tid; idx < 4352; idx += 256) {  // 8ci*17lr*32p
      int p = idx & 31, r = idx >> 5;              // r<136
      int ci = r & 7, lr = r >> 3;
      int ih = 2 * oh0 - 1 + lr;
      float2 v = make_float2(0.f, 0.f);
      if ((unsigned)ih < 64u)
        v = *(const float2*)&h1[((b * 128 + ci0 + ci) * 64 + ih) * 64 + 2 * p];
      E[ci][lr][p] = v.x;
      O[ci][lr][p + 1] = v.y;
    }
    if (tid < 136) {
      int ci = tid & 7, lr = tid >> 3;
      O[ci][lr][0] = 0.f;
    }
    __syncthreads();

    for (int ci = 0; ci < 8; ci++) {
#pragma unroll
      for (int ky = 0; ky < 3; ky++) {
        int lr = 2 * ohl + ky;
        float4 ev = *(float4*)&E[ci][lr][ow0];
        float4 od = *(float4*)&O[ci][lr][ow0];
        float o4 = O[ci][lr][ow0 + 4];
        const float* wr = w2t + ((ci0 + ci) * 9 + ky * 3) * 128 + coB;
#pragma unroll
        for (int q = 0; q < 8; q++) {
          float wa = wr[q], wb = wr[128 + q], wc = wr[256 + q];
          acc[q].x += wa * od.x + wb * ev.x + wc * od.y;
          acc[q].y += wa * od.y + wb * ev.y + wc * od.z;
          acc[q].z += wa * od.z + wb * ev.z + wc * od.w;
          acc[q].w += wa * od.w + wb * ev.w + wc * o4;
        }
      }
    }
  }
#pragma unroll
  for (int q = 0; q < 8; q++) {
    float4 r4;
    r4.x = fmaxf(acc[q].x, 0.f);
    r4.y = fmaxf(acc[q].y, 0.f);
    r4.z = fmaxf(acc[q].z, 0.f);
    r4.w = fmaxf(acc[q].w, 0.f);
    *(float4*)&h2[((b * 128 + coB + q) * 32 + oh) * 32 + ow0] = r4;
  }
}

// ---------- pool: h2 (b,ci,32,32) -> hp[ci][b*64+site], 4x4 mean ----------
// grid (128 ci, 32 b), block 64 (one wave)
__global__ __launch_bounds__(64) void k_pool(const float* __restrict__ h2,
                                             float* __restrict__ hp) {
  int ci = blockIdx.x, b = blockIdx.y, l = threadIdx.x;
  const float4* src = (const float4*)&h2[(b * 128 + ci) * 1024];
  float part[4];
#pragma unroll
  for (int i = 0; i < 4; i++) {
    float4 v = src[i * 64 + l];
    part[i] = v.x + v.y + v.z + v.w;  // (row = 8i + (l>>3), bj = l&7)
  }
#pragma unroll
  for (int i = 0; i < 4; i++) {
    part[i] += __shfl_xor(part[i], 8, 64);
    part[i] += __shfl_xor(part[i], 16, 64);
  }
  if ((l & 24) == 0) {  // lanes {0..7, 32..39}
#pragma unroll
    for (int i = 0; i < 4; i++) {
      int bi = 2 * i + (l >> 5);
      hp[ci * 2048 + b * 64 + bi * 8 + (l & 7)] = part[i] * 0.0625f;
    }
  }
}

// ---------- proj: z_e[b][d][site] = wp . hp + pb  (64d x 64site x 128k) ----
// grid 32 (b), block 256, thread 4d x 4site
__global__ __launch_bounds__(256) void k_proj(const float* __restrict__ hp,
                                              const float* __restrict__ wpT,
                                              const float* __restrict__ pb,
                                              float* __restrict__ z_e_out) {
  __shared__ float Ws[64][64];
  __shared__ float Hs[64][64];
  int b = blockIdx.x, tid = threadIdx.x;
  int ty = tid >> 4, tx = tid & 15;
  int d0 = ty * 4, s0 = tx * 4;
  float4 acc[4];
#pragma unroll
  for (int i = 0; i < 4; i++) acc[i] = make_float4(0.f, 0.f, 0.f, 0.f);
  for (int k0 = 0; k0 < 128; k0 += 64) {
    __syncthreads();
    for (int idx = tid; idx < 4096; idx += 256) {
      int kk = idx >> 6, dd = idx & 63;
      Ws[kk][dd] = wpT[(k0 + kk) * 64 + dd];
    }
    for (int idx = tid; idx < 4096; idx += 256) {
      int kk = idx >> 6, ss = idx & 63;
      Hs[kk][ss] = hp[(k0 + kk) * 2048 + b * 64 + ss];
    }
    __syncthreads();
    for (int kk = 0; kk < 64; kk++) {
      float4 a = *(float4*)&Ws[kk][d0];
      float4 bb = *(float4*)&Hs[kk][s0];
      acc[0].x += a.x * bb.x; acc[0].y += a.x * bb.y; acc[0].z += a.x * bb.z; acc[0].w += a.x * bb.w;
      acc[1].x += a.y * bb.x; acc[1].y += a.y * bb.y; acc[1].z += a.y * bb.z; acc[1].w += a.y * bb.w;
      acc[2].x += a.z * bb.x; acc[2].y += a.z * bb.y; acc[2].z += a.z * bb.z; acc[2].w += a.z * bb.w;
      acc[3].x += a.w * bb.x; acc[3].y += a.w * bb.y; acc[3].z += a.w * bb.z; acc[3].w += a.w * bb.w;
    }
  }
#pragma unroll
  for (int i = 0; i < 4; i++) {
    float bv = pb[d0 + i];
    float4 r4 = make_float4(acc[i].x + bv, acc[i].y + bv, acc[i].z + bv, acc[i].w + bv);
    *(float4*)&z_e_out[(b * 64 + d0 + i) * 64 + s0] = r4;
  }
}

// ---------- VQ: argmin over 512 codes, loss accum ----------
// grid 2048 (n), block 64 (one wave)  [unchanged from verified R1]
__global__ __launch_bounds__(64) void k_vq(const float* __restrict__ z_e,
                                           const float* __restrict__ cb,
                                           float* __restrict__ idx_f,
                                           int* __restrict__ idx_i,
                                           float* __restrict__ loss_acc) {
  __shared__ float zs[64];
  int n = blockIdx.x, lane = threadIdx.x;
  int b = n >> 6, pi = n & 63;
  zs[lane] = z_e[(b * 64 + lane) * 64 + pi];
  __syncthreads();
  double best = 1e300;
  int bi = 0;
  for (int j = 0; j < 8; j++) {
    int k = j * 64 + lane;
    const float* c = &cb[k * 64];
    double acc = 0.0;
#pragma unroll 8
    for (int d = 0; d < 64; d++) {
      double diff = (double)zs[d] - (double)c[d];
      acc += diff * diff;
    }
    if (acc < best) { best = acc; bi = k; }
  }
  for (int m = 1; m < 64; m <<= 1) {
    double ob = __shfl_xor(best, m, 64);
    int oi = __shfl_xor(bi, m, 64);
    if (ob < best || (ob == best && oi < bi)) { best = ob; bi = oi; }
  }
  float e = cb[bi * 64 + lane] - zs[lane];
  float sq = e * e;
  for (int m = 1; m < 64; m <<= 1) sq += __shfl_xor(sq, m, 64);
  if (lane == 0) {
    idx_f[n] = (float)bi;
    idx_i[n] = bi;
    atomicAdd(loss_acc, sq);
  }
}

__global__ void k_loss(const float* __restrict__ loss_acc, float* __restrict__ out_loss) {
  out_loss[0] = loss_acc[0] * 1.25f / 131072.0f;
}

// ---------- dproj(1x1, 64->128) + relu -> Yr (32,128,64) ----------
__global__ __launch_bounds__(128) void k_dproj(const int* __restrict__ idx_i,
                                               const float* __restrict__ cb,
                                               const float* __restrict__ wdT,
                                               const float* __restrict__ db,
                                               float* __restrict__ Yr) {
  __shared__ float zq[64];
  int n = blockIdx.x, tid = threadIdx.x;
  int b = n >> 6, pi = n & 63;
  int id = idx_i[n];
  if (tid < 64) zq[tid] = cb[id * 64 + tid];
  __syncthreads();
  float acc = db[tid];
#pragma unroll 4
  for (int d = 0; d < 64; d++) acc += wdT[d * 128 + tid] * zq[d];
  Yr[(b * 128 + tid) * 64 + pi] = fmaxf(acc, 0.f);
}

// ---------- dec: G[pq][n][co] = sum_ci A[pq][ci][co] * Yshift[ci][n] ----------
// grid (32, 25): x = co_t(4) + n_t(8)*4 ... x&3 = co_t, x>>2 = n_t; y = pq.
// block 256; wave owns 8 co; lane owns 4 n.
__global__ __launch_bounds__(256) void k_dec(const float* __restrict__ Yr,
                                             const float* __restrict__ A,
                                             float* __restrict__ G) {
  __shared__ float Bs[16][256];
  int bx = blockIdx.x;
  int co_t = bx & 3, n_t = bx >> 2;
  int pq = blockIdx.y;
  int py = pq / 5, px = pq - py * 5;
  int dy = (py == 0) ? -1 : ((py == 4) ? 1 : 0);
  int dx = (px == 0) ? -1 : ((px == 4) ? 1 : 0);
  int tid = threadIdx.x;
  int wv = __builtin_amdgcn_readfirstlane(tid >> 6);
  int l = tid & 63;
  int coB = co_t * 32 + wv * 8;
  int nB = n_t * 256;

  float4 acc[8];
#pragma unroll
  for (int q = 0; q < 8; q++) acc[q] = make_float4(0.f, 0.f, 0.f, 0.f);

  for (int ci0 = 0; ci0 < 128; ci0 += 16) {
    __syncthreads();
    for (int idx = tid; idx < 4096; idx += 256) {
      int nn = idx & 255, kk = idx >> 8;
      int n = nB + nn;
      int bb = n >> 6, s = n & 63;
      int sy = (s >> 3) + dy, sx = (s & 7) + dx;
      float v = 0.f;
      if ((unsigned)sy < 8u && (unsigned)sx < 8u)
        v = Yr[(bb * 128 + ci0 + kk) * 64 + sy * 8 + sx];
      Bs[kk][nn] = v;
    }
    __syncthreads();
    for (int kk = 0; kk < 16; kk++) {
      float4 bb4 = *(float4*)&Bs[kk][l * 4];
      const float* ar = A + pq * 16384 + (ci0 + kk) * 128 + coB;
#pragma unroll
      for (int q = 0; q < 8; q++) {
        float av = ar[q];
        acc[q].x += av * bb4.x;
        acc[q].y += av * bb4.y;
        acc[q].z += av * bb4.z;
        acc[q].w += av * bb4.w;
      }
    }
  }
  // store: G[pq][n][co], transpose acc (q-major -> n-major)
  int nbase = nB + l * 4;
#pragma unroll
  for (int j = 0; j < 4; j++) {
    float* gp = &G[(pq * 2048 + nbase + j) * 128 + coB];
    float4 g0, g1;
    const float* af = (const float*)acc;
    g0 = make_float4(af[0 * 4 + j], af[1 * 4 + j], af[2 * 4 + j], af[3 * 4 + j]);
    g1 = make_float4(af[4 * 4 + j], af[5 * 4 + j], af[6 * 4 + j], af[7 * 4 + j]);
    *(float4*)gp = g0;
    *(float4*)(gp + 4) = g1;
  }
}

// ---------- out: combine G per class, bias+relu, 1x1 conv to 3ch, splat ------
// grid (8,8,32) = (bj, bi, b), block 256
__global__ __launch_bounds__(256) void k_out(const float* __restrict__ G,
                                             const float* __restrict__ bc1,
                                             const float* __restrict__ w3,
                                             const float* __restrict__ b3,
                                             float* __restrict__ xhat) {
  __shared__ float Tb[9][128];
  __shared__ float part[9][3][8];
  __shared__ float vals[9][3];
  int bj = blockIdx.x, bi = blockIdx.y, b = blockIdx.z;
  int s = bi * 8 + bj;
  int n = b * 64 + s;
  int tid = threadIdx.x;
  int co = tid & 127, h = tid >> 7;
  const int rset[3][2] = {{0, 1}, {2, 2}, {3, 4}};
  const int rcnt[3] = {2, 1, 2};
  for (int cls = h; cls < 9; cls += 2) {
    int r = cls / 3, c = cls - r * 3;
    float sum = bc1[co];
    for (int iy = 0; iy < rcnt[r]; iy++) {
      int py = rset[r][iy];
      for (int ix = 0; ix < rcnt[c]; ix++) {
        int px = rset[c][ix];
        sum += G[((py * 5 + px) * 2048 + n) * 128 + co];
      }
    }
    Tb[cls][co] = fmaxf(sum, 0.f);
  }
  __syncthreads();
  if (tid < 216) {
    int cls = tid / 24, rem = tid - cls * 24;
    int cc = rem >> 3, seg = rem & 7;
    float ss = 0.f;
#pragma unroll
    for (int d = 0; d < 16; d++) ss += w3[cc * 128 + seg * 16 + d] * Tb[cls][seg * 16 + d];
    part[cls][cc][seg] = ss;
  }
  __syncthreads();
  if (tid < 27) {
    int cls = tid / 3, cc = tid - cls * 3;
    float ss = b3[cc];
#pragma unroll
    for (int seg = 0; seg < 8; seg++) ss += part[cls][cc][seg];
    vals[cls][cc] = ss;
  }
  __syncthreads();
  for (int i = tid; i < 768; i += 256) {
    int cc = i >> 8, p = i & 255;
    int ry = p >> 4, rx = p & 15;
    int rcls = (ry == 0) ? 0 : ((ry == 15) ? 2 : 1);
    int ccls = (rx == 0) ? 0 : ((rx == 15) ? 2 : 1);
    xhat[((b * 3 + cc) * 128 + bi * 16 + ry) * 128 + bj * 16 + rx] =
        vals[rcls * 3 + ccls][cc];
  }
}

extern "C" void kernel_launch(void* const* d_in, const int* in_sizes, int n_in,
                              void* d_out, int out_size, void* d_ws, size_t ws_size,
                              hipStream_t stream) {
  const float* x   = (const float*)d_in[0];
  const float* w1  = (const float*)d_in[1];
  const float* b1  = (const float*)d_in[2];
  const float* w2  = (const float*)d_in[3];
  const float* b2  = (const float*)d_in[4];
  const float* wp  = (const float*)d_in[5];
  const float* pb  = (const float*)d_in[6];
  const float* cb  = (const float*)d_in[7];
  const float* wd  = (const float*)d_in[8];
  const float* db  = (const float*)d_in[9];
  const float* wc1 = (const float*)d_in[10];
  const float* bc1 = (const float*)d_in[11];
  const float* wc2 = (const float*)d_in[12];
  const float* bc2 = (const float*)d_in[13];
  float* out = (float*)d_out;
  float* ws  = (float*)d_ws;

  // workspace (floats). h1 region [0,16777216) is reused after conv2 by
  // G/A/hp/Yr/idxi/lossacc (all sub-offsets within it).
  float* h1      = ws;                    // 16777216
  float* G       = ws;                    // 6553600   (after conv2)
  float* A       = ws + 6553600;          // 409600    (after conv2)
  float* hp      = ws + 6963200;          // 262144    (after conv2)
  float* Yr      = ws + 7225344;          // 262144    (after conv2)
  int*   idxi    = (int*)(ws + 7487488);  // 2048      (after conv2)
  float* lossacc = ws + 7489536;          // 1         (after conv2)
  float* h2      = ws + 16777216;         // 4194304
  float* w2t     = ws + 20971520;         // 147456
  float* w1t     = ws + 21118976;         // 3456
  float* wpT     = ws + 21122432;         // 8192
  float* wdT     = ws + 21130624;         // 8192  -> end 21138816 floats

  float* o_xhat = out;
  float* o_idx  = out + 1572864;
  float* o_loss = out + 1574912;
  float* o_ze   = out + 1574913;

  k_prep<<<dim3(654), 256, 0, stream>>>(w2, w1, wp, wd, w2t, w1t, wpT, wdT);
  k_conv1<<<dim3(4, 16, 32), 256, 0, stream>>>(x, w1t, b1, h1);
  k_conv2<<<dim3(4, 4, 32), 256, 0, stream>>>(h1, w2t, b2, h2);
  // h1 region free from here
  hipMemsetAsync(lossacc, 0, sizeof(float), stream);
  k_prep2<<<dim3(1600), 256, 0, stream>>>(wc1, A);
  k_pool<<<dim3(128, 32), 64, 0, stream>>>(h2, hp);
  k_proj<<<dim3(32), 256, 0, stream>>>(hp, wpT, pb, o_ze);
  k_vq<<<dim3(2048), 64, 0, stream>>>(o_ze, cb, o_idx, idxi, lossacc);
  k_loss<<<dim3(1), 1, 0, stream>>>(lossacc, o_loss);
  k_dproj<<<dim3(2048), 128, 0, stream>>>(idxi, cb, wdT, db, Yr);
  k_dec<<<dim3(32, 25), 256, 0, stream>>>(Yr, A, G);
  k_out<<<dim3(8, 8, 32), 256, 0, stream>>>(G, bc1, wc2, bc2, o_xhat);
}

// Round 3
// 414.396 us; speedup vs baseline: 1.3427x; 1.2112x over previous
//
#include <hip/hip_runtime.h>
#include <math.h>

// ---------------------------------------------------------------------------
// VQVAE forward, fp32 end-to-end. v3: coalesced codebook (cbT) for VQ,
// conv2 with 1024-block grid + fmaf chains, wave-uniform weights (s_load),
// decoder as 25 uniform batched GEMMs combined per-class in k_out.
// ---------------------------------------------------------------------------

// ---------- prep: transposes (w2t, w1t, wpT, wdT) ----------
__global__ __launch_bounds__(256) void k_prep(const float* __restrict__ w2,
                                              const float* __restrict__ w1,
                                              const float* __restrict__ wp,
                                              const float* __restrict__ wd,
                                              float* __restrict__ w2t,
                                              float* __restrict__ w1t,
                                              float* __restrict__ wpT,
                                              float* __restrict__ wdT) {
  int i = blockIdx.x * 256 + threadIdx.x;
  if (i < 147456) {  // w2t[k][co] = w2[co][k], k<1152
    int k = i >> 7, co = i & 127;
    w2t[i] = w2[co * 1152 + k];
  }
  int j = i - 147456;
  if (j >= 0 && j < 3456) {  // w1t[t][co] = w1[co][t], t<27
    int t = j >> 7, co = j & 127;
    w1t[j] = w1[co * 27 + t];
  }
  int j2 = i - 150912;
  if (j2 >= 0 && j2 < 8192) {  // wpT[k][d] = wp[d][k]
    int k = j2 >> 6, d = j2 & 63;
    wpT[j2] = wp[d * 128 + k];
  }
  int j3 = i - 159104;
  if (j3 >= 0 && j3 < 8192) {  // wdT[d][co] = wd[co][d]
    int d = j3 >> 7, co = j3 & 127;
    wdT[j3] = wd[co * 64 + d];
  }
}

// ---------- prep2 (after conv2): aggregate dconv1 weights + transpose cb ----
__global__ __launch_bounds__(256) void k_prep2(const float* __restrict__ wd1,
                                               const float* __restrict__ cb,
                                               float* __restrict__ A,
                                               float* __restrict__ cbT) {
  int i = blockIdx.x * 256 + threadIdx.x;
  const int ymask[5] = {1, 6, 7, 3, 4};  // {ky0},{ky1,2},{all},{ky0,1},{ky2}
  if (i < 409600) {
    int pq = i >> 14, rem = i & 16383;
    int ci = rem >> 7, co = rem & 127;
    int py = pq / 5, px = pq - py * 5;
    int my = ymask[py], mx = ymask[px];
    float s = 0.f;
    for (int ky = 0; ky < 3; ky++)
      if (my & (1 << ky))
        for (int kx = 0; kx < 3; kx++)
          if (mx & (1 << kx)) s += wd1[((co * 128 + ci) * 3 + ky) * 3 + kx];
    A[i] = s;
  }
  int j = i - 409600;
  if (j >= 0 && j < 32768) {  // cbT[d][k] = cb[k][d]
    int d = j >> 9, k = j & 511;
    cbT[d * 512 + k] = cb[k * 64 + d];
  }
}

// ---------- conv1: (32,3,128,128) -> (32,128,64,64), 3x3 s2 p1, relu ----------
// grid (4 co_t, 16 oh_t, 32 b), block 256. Wave owns 8 co; lane = 4 ow x 1 oh.
__global__ __launch_bounds__(256) void k_conv1(const float* __restrict__ x,
                                               const float* __restrict__ w1t,
                                               const float* __restrict__ b1,
                                               float* __restrict__ h1) {
  __shared__ float E[3][9][68];  // even cols: E[ci][lr][w] = x[ih][2w]
  __shared__ float O[3][9][68];  // odd cols:  O[ci][lr][u] = x[ih][2u-1]
  int co_t = blockIdx.x, oh_t = blockIdx.y, b = blockIdx.z;
  int oh0 = oh_t * 4;
  int tid = threadIdx.x;
  int wv = __builtin_amdgcn_readfirstlane(tid >> 6);
  int l = tid & 63;
  int coB = co_t * 32 + wv * 8;

  for (int idx = tid; idx < 1728; idx += 256) {  // 3ci*9lr*64p
    int p = idx & 63, r = idx >> 6;              // r<27
    int ci = r / 9, lr = r - ci * 9;
    int ih = 2 * oh0 - 1 + lr;
    float2 v = make_float2(0.f, 0.f);
    if ((unsigned)ih < 128u)
      v = *(const float2*)&x[((b * 3 + ci) * 128 + ih) * 128 + 2 * p];
    E[ci][lr][p] = v.x;
    O[ci][lr][p + 1] = v.y;
  }
  if (tid < 27) {
    int ci = tid / 9, lr = tid - ci * 9;
    O[ci][lr][0] = 0.f;  // iw = -1 pad
  }
  __syncthreads();

  int ohl = l >> 4, ow0 = (l & 15) * 4;
  int oh = oh0 + ohl;
  float4 acc[8];
#pragma unroll
  for (int q = 0; q < 8; q++) {
    float bv = b1[coB + q];
    acc[q] = make_float4(bv, bv, bv, bv);
  }
#pragma unroll
  for (int ci = 0; ci < 3; ci++) {
#pragma unroll
    for (int ky = 0; ky < 3; ky++) {
      int lr = 2 * ohl + ky;
      float4 ev = *(float4*)&E[ci][lr][ow0];
      float4 od = *(float4*)&O[ci][lr][ow0];
      float o4 = O[ci][lr][ow0 + 4];
      const float* wr = w1t + (ci * 9 + ky * 3) * 128 + coB;
#pragma unroll
      for (int q = 0; q < 8; q++) {
        float wa = wr[q], wb = wr[128 + q], wc = wr[256 + q];
        acc[q].x = fmaf(wa, od.x, acc[q].x);
        acc[q].x = fmaf(wb, ev.x, acc[q].x);
        acc[q].x = fmaf(wc, od.y, acc[q].x);
        acc[q].y = fmaf(wa, od.y, acc[q].y);
        acc[q].y = fmaf(wb, ev.y, acc[q].y);
        acc[q].y = fmaf(wc, od.z, acc[q].y);
        acc[q].z = fmaf(wa, od.z, acc[q].z);
        acc[q].z = fmaf(wb, ev.z, acc[q].z);
        acc[q].z = fmaf(wc, od.w, acc[q].z);
        acc[q].w = fmaf(wa, od.w, acc[q].w);
        acc[q].w = fmaf(wb, ev.w, acc[q].w);
        acc[q].w = fmaf(wc, o4,   acc[q].w);
      }
    }
  }
#pragma unroll
  for (int q = 0; q < 8; q++) {
    float4 r4;
    r4.x = fmaxf(acc[q].x, 0.f);
    r4.y = fmaxf(acc[q].y, 0.f);
    r4.z = fmaxf(acc[q].z, 0.f);
    r4.w = fmaxf(acc[q].w, 0.f);
    *(float4*)&h1[((b * 128 + coB + q) * 64 + oh) * 64 + ow0] = r4;
  }
}

// ---------- conv2: (32,128,64,64) -> (32,128,32,32), 3x3 s2 p1, relu ----------
// grid (4 co_t, 8 oh_t, 32 b) = 1024 blocks. Wave owns 8 co; lane = 2 ow x 4 oh.
__global__ __launch_bounds__(256) void k_conv2(const float* __restrict__ h1,
                                               const float* __restrict__ w2t,
                                               const float* __restrict__ b2,
                                               float* __restrict__ h2) {
  __shared__ float E[8][9][36];
  __shared__ float O[8][9][36];
  int co_t = blockIdx.x, oh_t = blockIdx.y, b = blockIdx.z;
  int oh0 = oh_t * 4;
  int tid = threadIdx.x;
  int wv = __builtin_amdgcn_readfirstlane(tid >> 6);
  int l = tid & 63;
  int coB = co_t * 32 + wv * 8;
  int ohl = l >> 4, ow0 = (l & 15) * 2;
  int oh = oh0 + ohl;

  float2 acc[8];
#pragma unroll
  for (int q = 0; q < 8; q++) {
    float bv = b2[coB + q];
    acc[q] = make_float2(bv, bv);
  }

  for (int ci0 = 0; ci0 < 128; ci0 += 8) {
    __syncthreads();
    for (int idx = tid; idx < 2304; idx += 256) {  // 8ci*9lr*32p
      int p = idx & 31, r = idx >> 5;              // r<72
      int ci = r & 7, lr = r >> 3;
      int ih = 2 * oh0 - 1 + lr;
      float2 v = make_float2(0.f, 0.f);
      if ((unsigned)ih < 64u)
        v = *(const float2*)&h1[((b * 128 + ci0 + ci) * 64 + ih) * 64 + 2 * p];
      E[ci][lr][p] = v.x;
      O[ci][lr][p + 1] = v.y;
    }
    if (tid < 72) {
      int ci = tid & 7, lr = tid >> 3;
      O[ci][lr][0] = 0.f;
    }
    __syncthreads();

    for (int ci = 0; ci < 8; ci++) {
#pragma unroll
      for (int ky = 0; ky < 3; ky++) {
        int lr = 2 * ohl + ky;
        float2 ev = *(float2*)&E[ci][lr][ow0];
        float2 od = *(float2*)&O[ci][lr][ow0];
        float o2 = O[ci][lr][ow0 + 2];
        const float* wr = w2t + ((ci0 + ci) * 9 + ky * 3) * 128 + coB;
#pragma unroll
        for (int q = 0; q < 8; q++) {
          float wa = wr[q], wb = wr[128 + q], wc = wr[256 + q];
          acc[q].x = fmaf(wa, od.x, acc[q].x);
          acc[q].x = fmaf(wb, ev.x, acc[q].x);
          acc[q].x = fmaf(wc, od.y, acc[q].x);
          acc[q].y = fmaf(wa, od.y, acc[q].y);
          acc[q].y = fmaf(wb, ev.y, acc[q].y);
          acc[q].y = fmaf(wc, o2,   acc[q].y);
        }
      }
    }
  }
#pragma unroll
  for (int q = 0; q < 8; q++) {
    float2 r2 = make_float2(fmaxf(acc[q].x, 0.f), fmaxf(acc[q].y, 0.f));
    *(float2*)&h2[((b * 128 + coB + q) * 32 + oh) * 32 + ow0] = r2;
  }
}

// ---------- pool: h2 (b,ci,32,32) -> hp[ci][b*64+site], 4x4 mean ----------
// grid (128 ci, 32 b), block 64 (one wave)
__global__ __launch_bounds__(64) void k_pool(const float* __restrict__ h2,
                                             float* __restrict__ hp) {
  int ci = blockIdx.x, b = blockIdx.y, l = threadIdx.x;
  const float4* src = (const float4*)&h2[(b * 128 + ci) * 1024];
  float part[4];
#pragma unroll
  for (int i = 0; i < 4; i++) {
    float4 v = src[i * 64 + l];
    part[i] = v.x + v.y + v.z + v.w;  // (row = 8i + (l>>3), bj = l&7)
  }
#pragma unroll
  for (int i = 0; i < 4; i++) {
    part[i] += __shfl_xor(part[i], 8, 64);
    part[i] += __shfl_xor(part[i], 16, 64);
  }
  if ((l & 24) == 0) {  // lanes {0..7, 32..39}
#pragma unroll
    for (int i = 0; i < 4; i++) {
      int bi = 2 * i + (l >> 5);
      hp[ci * 2048 + b * 64 + bi * 8 + (l & 7)] = part[i] * 0.0625f;
    }
  }
}

// ---------- proj: z_e[b][d][site] = wp . hp + pb  (64d x 64site x 128k) ----
// grid 32 (b), block 256, thread 4d x 4site
__global__ __launch_bounds__(256) void k_proj(const float* __restrict__ hp,
                                              const float* __restrict__ wpT,
                                              const float* __restrict__ pb,
                                              float* __restrict__ z_e_out) {
  __shared__ float Ws[64][64];
  __shared__ float Hs[64][64];
  int b = blockIdx.x, tid = threadIdx.x;
  int ty = tid >> 4, tx = tid & 15;
  int d0 = ty * 4, s0 = tx * 4;
  float4 acc[4];
#pragma unroll
  for (int i = 0; i < 4; i++) acc[i] = make_float4(0.f, 0.f, 0.f, 0.f);
  for (int k0 = 0; k0 < 128; k0 += 64) {
    __syncthreads();
    for (int idx = tid; idx < 4096; idx += 256) {
      int kk = idx >> 6, dd = idx & 63;
      Ws[kk][dd] = wpT[(k0 + kk) * 64 + dd];
    }
    for (int idx = tid; idx < 4096; idx += 256) {
      int kk = idx >> 6, ss = idx & 63;
      Hs[kk][ss] = hp[(k0 + kk) * 2048 + b * 64 + ss];
    }
    __syncthreads();
    for (int kk = 0; kk < 64; kk++) {
      float4 a = *(float4*)&Ws[kk][d0];
      float4 bb = *(float4*)&Hs[kk][s0];
      acc[0].x = fmaf(a.x, bb.x, acc[0].x); acc[0].y = fmaf(a.x, bb.y, acc[0].y);
      acc[0].z = fmaf(a.x, bb.z, acc[0].z); acc[0].w = fmaf(a.x, bb.w, acc[0].w);
      acc[1].x = fmaf(a.y, bb.x, acc[1].x); acc[1].y = fmaf(a.y, bb.y, acc[1].y);
      acc[1].z = fmaf(a.y, bb.z, acc[1].z); acc[1].w = fmaf(a.y, bb.w, acc[1].w);
      acc[2].x = fmaf(a.z, bb.x, acc[2].x); acc[2].y = fmaf(a.z, bb.y, acc[2].y);
      acc[2].z = fmaf(a.z, bb.z, acc[2].z); acc[2].w = fmaf(a.z, bb.w, acc[2].w);
      acc[3].x = fmaf(a.w, bb.x, acc[3].x); acc[3].y = fmaf(a.w, bb.y, acc[3].y);
      acc[3].z = fmaf(a.w, bb.z, acc[3].z); acc[3].w = fmaf(a.w, bb.w, acc[3].w);
    }
  }
#pragma unroll
  for (int i = 0; i < 4; i++) {
    float bv = pb[d0 + i];
    float4 r4 = make_float4(acc[i].x + bv, acc[i].y + bv, acc[i].z + bv, acc[i].w + bv);
    *(float4*)&z_e_out[(b * 64 + d0 + i) * 64 + s0] = r4;
  }
}

// ---------- VQ: argmin over 512 codes (coalesced via cbT), loss accum ----------
// grid 2048 (n), block 64 (one wave)
__global__ __launch_bounds__(64) void k_vq(const float* __restrict__ z_e,
                                           const float* __restrict__ cbT,
                                           const float* __restrict__ cb,
                                           float* __restrict__ idx_f,
                                           int* __restrict__ idx_i,
                                           float* __restrict__ loss_acc) {
  __shared__ float zs[64];
  int n = blockIdx.x, lane = threadIdx.x;
  int b = n >> 6, pi = n & 63;
  zs[lane] = z_e[(b * 64 + lane) * 64 + pi];
  __syncthreads();
  double best = 1e300;
  int bi = 0;
#pragma unroll 2
  for (int j = 0; j < 8; j++) {
    int k = j * 64 + lane;
    double acc = 0.0;
#pragma unroll 8
    for (int d = 0; d < 64; d++) {
      float c = cbT[d * 512 + k];  // consecutive lanes -> consecutive addrs
      double diff = (double)zs[d] - (double)c;
      acc = fma(diff, diff, acc);
    }
    if (acc < best) { best = acc; bi = k; }  // ascending k: first-min kept
  }
  for (int m = 1; m < 64; m <<= 1) {
    double ob = __shfl_xor(best, m, 64);
    int oi = __shfl_xor(bi, m, 64);
    if (ob < best || (ob == best && oi < bi)) { best = ob; bi = oi; }
  }
  float e = cb[bi * 64 + lane] - zs[lane];
  float sq = e * e;
  for (int m = 1; m < 64; m <<= 1) sq += __shfl_xor(sq, m, 64);
  if (lane == 0) {
    idx_f[n] = (float)bi;
    idx_i[n] = bi;
    atomicAdd(loss_acc, sq);
  }
}

__global__ void k_loss(const float* __restrict__ loss_acc, float* __restrict__ out_loss) {
  out_loss[0] = loss_acc[0] * 1.25f / 131072.0f;
}

// ---------- dproj(1x1, 64->128) + relu -> Yr (32,128,64) ----------
__global__ __launch_bounds__(128) void k_dproj(const int* __restrict__ idx_i,
                                               const float* __restrict__ cb,
                                               const float* __restrict__ wdT,
                                               const float* __restrict__ db,
                                               float* __restrict__ Yr) {
  __shared__ float zq[64];
  int n = blockIdx.x, tid = threadIdx.x;
  int b = n >> 6, pi = n & 63;
  int id = idx_i[n];
  if (tid < 64) zq[tid] = cb[id * 64 + tid];
  __syncthreads();
  float acc = db[tid];
#pragma unroll 4
  for (int d = 0; d < 64; d++) acc = fmaf(wdT[d * 128 + tid], zq[d], acc);
  Yr[(b * 128 + tid) * 64 + pi] = fmaxf(acc, 0.f);
}

// ---------- dec: G[pq][n][co] = sum_ci A[pq][ci][co] * Yshift[ci][n] ----------
// grid (32, 25): x&3 = co_t, x>>2 = n_t; y = pq. block 256.
__global__ __launch_bounds__(256) void k_dec(const float* __restrict__ Yr,
                                             const float* __restrict__ A,
                                             float* __restrict__ G) {
  __shared__ float Bs[16][256];
  int bx = blockIdx.x;
  int co_t = bx & 3, n_t = bx >> 2;
  int pq = blockIdx.y;
  int py = pq / 5, px = pq - py * 5;
  int dy = (py == 0) ? -1 : ((py == 4) ? 1 : 0);
  int dx = (px == 0) ? -1 : ((px == 4) ? 1 : 0);
  int tid = threadIdx.x;
  int wv = __builtin_amdgcn_readfirstlane(tid >> 6);
  int l = tid & 63;
  int coB = co_t * 32 + wv * 8;
  int nB = n_t * 256;

  float4 acc[8];
#pragma unroll
  for (int q = 0; q < 8; q++) acc[q] = make_float4(0.f, 0.f, 0.f, 0.f);

  for (int ci0 = 0; ci0 < 128; ci0 += 16) {
    __syncthreads();
    for (int idx = tid; idx < 4096; idx += 256) {
      int nn = idx & 255, kk = idx >> 8;
      int n = nB + nn;
      int bb = n >> 6, s = n & 63;
      int sy = (s >> 3) + dy, sx = (s & 7) + dx;
      float v = 0.f;
      if ((unsigned)sy < 8u && (unsigned)sx < 8u)
        v = Yr[(bb * 128 + ci0 + kk) * 64 + sy * 8 + sx];
      Bs[kk][nn] = v;
    }
    __syncthreads();
    for (int kk = 0; kk < 16; kk++) {
      float4 bb4 = *(float4*)&Bs[kk][l * 4];
      const float* ar = A + pq * 16384 + (ci0 + kk) * 128 + coB;
#pragma unroll
      for (int q = 0; q < 8; q++) {
        float av = ar[q];
        acc[q].x = fmaf(av, bb4.x, acc[q].x);
        acc[q].y = fmaf(av, bb4.y, acc[q].y);
        acc[q].z = fmaf(av, bb4.z, acc[q].z);
        acc[q].w = fmaf(av, bb4.w, acc[q].w);
      }
    }
  }
  int nbase = nB + l * 4;
#pragma unroll
  for (int j = 0; j < 4; j++) {
    float* gp = &G[(pq * 2048 + nbase + j) * 128 + coB];
    const float* af = (const float*)acc;
    float4 g0 = make_float4(af[0 * 4 + j], af[1 * 4 + j], af[2 * 4 + j], af[3 * 4 + j]);
    float4 g1 = make_float4(af[4 * 4 + j], af[5 * 4 + j], af[6 * 4 + j], af[7 * 4 + j]);
    *(float4*)gp = g0;
    *(float4*)(gp + 4) = g1;
  }
}

// ---------- out: combine G per class, bias+relu, 1x1 conv to 3ch, splat ------
// grid (8,8,32) = (bj, bi, b), block 256
__global__ __launch_bounds__(256) void k_out(const float* __restrict__ G,
                                             const float* __restrict__ bc1,
                                             const float* __restrict__ w3,
                                             const float* __restrict__ b3,
                                             float* __restrict__ xhat) {
  __shared__ float Tb[9][128];
  __shared__ float part[9][3][8];
  __shared__ float vals[9][3];
  int bj = blockIdx.x, bi = blockIdx.y, b = blockIdx.z;
  int s = bi * 8 + bj;
  int n = b * 64 + s;
  int tid = threadIdx.x;
  int co = tid & 127, h = tid >> 7;
  const int rset[3][2] = {{0, 1}, {2, 2}, {3, 4}};
  const int rcnt[3] = {2, 1, 2};
  for (int cls = h; cls < 9; cls += 2) {
    int r = cls / 3, c = cls - r * 3;
    float sum = bc1[co];
    for (int iy = 0; iy < rcnt[r]; iy++) {
      int py = rset[r][iy];
      for (int ix = 0; ix < rcnt[c]; ix++) {
        int px = rset[c][ix];
        sum += G[((py * 5 + px) * 2048 + n) * 128 + co];
      }
    }
    Tb[cls][co] = fmaxf(sum, 0.f);
  }
  __syncthreads();
  if (tid < 216) {
    int cls = tid / 24, rem = tid - cls * 24;
    int cc = rem >> 3, seg = rem & 7;
    float ss = 0.f;
#pragma unroll
    for (int d = 0; d < 16; d++) ss = fmaf(w3[cc * 128 + seg * 16 + d], Tb[cls][seg * 16 + d], ss);
    part[cls][cc][seg] = ss;
  }
  __syncthreads();
  if (tid < 27) {
    int cls = tid / 3, cc = tid - cls * 3;
    float ss = b3[cc];
#pragma unroll
    for (int seg = 0; seg < 8; seg++) ss += part[cls][cc][seg];
    vals[cls][cc] = ss;
  }
  __syncthreads();
  for (int i = tid; i < 768; i += 256) {
    int cc = i >> 8, p = i & 255;
    int ry = p >> 4, rx = p & 15;
    int rcls = (ry == 0) ? 0 : ((ry == 15) ? 2 : 1);
    int ccls = (rx == 0) ? 0 : ((rx == 15) ? 2 : 1);
    xhat[((b * 3 + cc) * 128 + bi * 16 + ry) * 128 + bj * 16 + rx] =
        vals[rcls * 3 + ccls][cc];
  }
}

extern "C" void kernel_launch(void* const* d_in, const int* in_sizes, int n_in,
                              void* d_out, int out_size, void* d_ws, size_t ws_size,
                              hipStream_t stream) {
  const float* x   = (const float*)d_in[0];
  const float* w1  = (const float*)d_in[1];
  const float* b1  = (const float*)d_in[2];
  const float* w2  = (const float*)d_in[3];
  const float* b2  = (const float*)d_in[4];
  const float* wp  = (const float*)d_in[5];
  const float* pb  = (const float*)d_in[6];
  const float* cb  = (const float*)d_in[7];
  const float* wd  = (const float*)d_in[8];
  const float* db  = (const float*)d_in[9];
  const float* wc1 = (const float*)d_in[10];
  const float* bc1 = (const float*)d_in[11];
  const float* wc2 = (const float*)d_in[12];
  const float* bc2 = (const float*)d_in[13];
  float* out = (float*)d_out;
  float* ws  = (float*)d_ws;

  // workspace (floats). h1 region [0,16777216) reused after conv2.
  float* h1      = ws;                    // 16777216
  float* G       = ws;                    // 6553600   (after conv2)
  float* A       = ws + 6553600;          // 409600    (after conv2)
  float* hp      = ws + 6963200;          // 262144    (after conv2)
  float* Yr      = ws + 7225344;          // 262144    (after conv2)
  float* cbT     = ws + 7487488;          // 32768     (after conv2)
  int*   idxi    = (int*)(ws + 7520256);  // 2048      (after conv2)
  float* lossacc = ws + 7522304;          // 1         (after conv2)
  float* h2      = ws + 16777216;         // 4194304
  float* w2t     = ws + 20971520;         // 147456
  float* w1t     = ws + 21118976;         // 3456
  float* wpT     = ws + 21122432;         // 8192
  float* wdT     = ws + 21130624;         // 8192  -> end 21138816 floats

  float* o_xhat = out;
  float* o_idx  = out + 1572864;
  float* o_loss = out + 1574912;
  float* o_ze   = out + 1574913;

  k_prep<<<dim3(654), 256, 0, stream>>>(w2, w1, wp, wd, w2t, w1t, wpT, wdT);
  k_conv1<<<dim3(4, 16, 32), 256, 0, stream>>>(x, w1t, b1, h1);
  k_conv2<<<dim3(4, 8, 32), 256, 0, stream>>>(h1, w2t, b2, h2);
  // h1 region free from here
  hipMemsetAsync(lossacc, 0, sizeof(float), stream);
  k_prep2<<<dim3(1728), 256, 0, stream>>>(wc1, cb, A, cbT);
  k_pool<<<dim3(128, 32), 64, 0, stream>>>(h2, hp);
  k_proj<<<dim3(32), 256, 0, stream>>>(hp, wpT, pb, o_ze);
  k_vq<<<dim3(2048), 64, 0, stream>>>(o_ze, cbT, cb, o_idx, idxi, lossacc);
  k_loss<<<dim3(1), 1, 0, stream>>>(lossacc, o_loss);
  k_dproj<<<dim3(2048), 128, 0, stream>>>(idxi, cb, wdT, db, Yr);
  k_dec<<<dim3(32, 25), 256, 0, stream>>>(Yr, A, G);
  k_out<<<dim3(8, 8, 32), 256, 0, stream>>>(G, bc1, wc2, bc2, o_xhat);
}